// Round 6
// baseline (553.598 us; speedup 1.0000x reference)
//
#include <hip/hip_runtime.h>

#define HDIM 2048
#define HH (HDIM * HDIM)          // 4,194,304
#define NIDX 2000000
#define BINS 256
#define NCOPY 16
#define TL_BLOCKS 2048            // tabloss grid (partials count)

// workspace layout (bytes)
#define PART_OFF     0                      // double partials[TL_BLOCKS] = 16 KB
#define CNT_OFF      16384                  // uint counter
#define HIST_OFF     20480                  // uint hist[NCOPY][6][256] = 96 KB
#define BITS_OFF     131072                 // sampled-pixel bitmap, HH/8 = 512 KB
#define PACKED_D_OFF 1048576                // uint packed_d[HH] = 16 MB
#define PACKED_R_OFF 17825792               // uint packed_r[HH] = 16 MB

// Node 1: zero hist/bits/counter + pack 3 channel bins (mask folded: v*0 -> bin 0)
// into bits 0..23 of one uint per pixel.
__global__ __launch_bounds__(256) void pack_kernel(
    const float* __restrict__ ref, const float* __restrict__ tgt,
    const float* __restrict__ msrc, const float* __restrict__ mtar,
    unsigned* __restrict__ packed_d, unsigned* __restrict__ packed_r,
    unsigned* __restrict__ hist, unsigned* __restrict__ bits,
    unsigned* __restrict__ counter)
{
    const int gtid = blockIdx.x * 256 + threadIdx.x;
    const int stride = gridDim.x * 256;

    if (gtid == 0) *counter = 0;
    for (int k = gtid; k < NCOPY * 6 * BINS; k += stride) hist[k] = 0;
    for (int k = gtid; k < HH / 32; k += stride) bits[k] = 0;

    for (int g = gtid; g < HH / 4; g += stride) {
        const int p = g * 4;
        const float4 ms4 = *(const float4*)(msrc + p);
        const float4 mt4 = *(const float4*)(mtar + p);
        const float ms[4] = {ms4.x, ms4.y, ms4.z, ms4.w};
        const float mt[4] = {mt4.x, mt4.y, mt4.z, mt4.w};
        unsigned od[4] = {0, 0, 0, 0}, orr[4] = {0, 0, 0, 0};
#pragma unroll
        for (int c = 0; c < 3; c++) {
            const float4 rv = *(const float4*)(ref + c * HH + p);
            const float4 tv = *(const float4*)(tgt + c * HH + p);
            const float r[4] = {rv.x, rv.y, rv.z, rv.w};
            const float tt[4] = {tv.x, tv.y, tv.z, tv.w};
#pragma unroll
            for (int k = 0; k < 4; k++) {
                // reference op order: ((x+1)*0.5)*255, then * mask
                const float vd = ((r[k] + 1.0f) * 0.5f) * 255.0f * ms[k];
                const float vr = ((tt[k] + 1.0f) * 0.5f) * 255.0f * mt[k];
                const unsigned bd = (unsigned)(int)fminf(fmaxf(floorf(vd), 0.0f), 255.0f);
                const unsigned br = (unsigned)(int)fminf(fmaxf(floorf(vr), 0.0f), 255.0f);
                od[k]  |= bd << (8 * c);
                orr[k] |= br << (8 * c);
            }
        }
        *(uint4*)(packed_d + p) = make_uint4(od[0], od[1], od[2], od[3]);
        *(uint4*)(packed_r + p) = make_uint4(orr[0], orr[1], orr[2], orr[3]);
    }
}

// Node 2: gather histogram (int4 index loads, 8 gathers in flight per thread)
// + sampled-pixel bitmap.
__global__ __launch_bounds__(256) void hist_kernel(
    const unsigned* __restrict__ packed_d, const unsigned* __restrict__ packed_r,
    const int* __restrict__ i0, const int* __restrict__ i1,
    const int* __restrict__ i2, const int* __restrict__ i3,
    unsigned* __restrict__ hist, unsigned* __restrict__ bits)
{
    __shared__ unsigned lhist[6 * BINS];
    for (int k = threadIdx.x; k < 6 * BINS; k += 256) lhist[k] = 0;
    __syncthreads();

    const int stride = gridDim.x * 256;
    for (int q = blockIdx.x * 256 + threadIdx.x; q < NIDX / 4; q += stride) {
        const int4 a = ((const int4*)i0)[q];
        const int4 b = ((const int4*)i1)[q];
        const int4 c = ((const int4*)i2)[q];
        const int4 d = ((const int4*)i3)[q];
        const int pd[4] = {a.x * HDIM + b.x, a.y * HDIM + b.y, a.z * HDIM + b.z, a.w * HDIM + b.w};
        const int pr[4] = {c.x * HDIM + d.x, c.y * HDIM + d.y, c.z * HDIM + d.z, c.w * HDIM + d.w};
        unsigned wd[4], wr[4];
#pragma unroll
        for (int k = 0; k < 4; k++) wd[k] = packed_d[pd[k]];
#pragma unroll
        for (int k = 0; k < 4; k++) wr[k] = packed_r[pr[k]];
#pragma unroll
        for (int k = 0; k < 4; k++) atomicOr(&bits[pd[k] >> 5], 1u << (pd[k] & 31));
#pragma unroll
        for (int k = 0; k < 4; k++) {
            atomicAdd(&lhist[           ( wd[k]        & 255u)], 1u);
            atomicAdd(&lhist[1 * BINS + ((wd[k] >> 8 ) & 255u)], 1u);
            atomicAdd(&lhist[2 * BINS + ((wd[k] >> 16) & 255u)], 1u);
            atomicAdd(&lhist[3 * BINS + ( wr[k]        & 255u)], 1u);
            atomicAdd(&lhist[4 * BINS + ((wr[k] >> 8 ) & 255u)], 1u);
            atomicAdd(&lhist[5 * BINS + ((wr[k] >> 16) & 255u)], 1u);
        }
    }
    __syncthreads();
    unsigned* h = hist + (blockIdx.x & (NCOPY - 1)) * (6 * BINS);
    for (int k = threadIdx.x; k < 6 * BINS; k += 256) {
        const unsigned v = lhist[k];
        if (v) atomicAdd(&h[k], v);
    }
}

// Node 3: per-block redundant transfer table (deterministic) + streaming loss
// + last-block finalize (threadfence + counter; agent-scope loads of partials).
__global__ __launch_bounds__(256) void tabloss_kernel(
    const float* __restrict__ inp, const float* __restrict__ ref,
    const float* __restrict__ msrc, const unsigned* __restrict__ hist,
    const unsigned* __restrict__ bits, double* __restrict__ partials,
    unsigned* __restrict__ counter, float* __restrict__ out)
{
    __shared__ float    cdf[6 * BINS];   // [0..3*BINS)=cdf_d, [3*BINS..6*BINS)=cdf_r
    __shared__ float    tab[3 * BINS];
    __shared__ double   red[256];
    __shared__ unsigned wsum[4];
    __shared__ unsigned is_last;

    const int t    = threadIdx.x;
    const int lane = t & 63;
    const int wid  = t >> 6;

    // ---- transfer table (validated R3 logic: exact int scan -> divide -> bsearch) ----
    for (int ch = 0; ch < 6; ch++) {
        unsigned x = 0;
#pragma unroll
        for (int cp = 0; cp < NCOPY; cp++) x += hist[cp * (6 * BINS) + ch * BINS + t];
#pragma unroll
        for (int d = 1; d < 64; d <<= 1) {
            const unsigned y = __shfl_up(x, d, 64);
            if (lane >= d) x += y;
        }
        if (lane == 63) wsum[wid] = x;
        __syncthreads();
        unsigned prefix = 0;
        for (int w = 0; w < wid; w++) prefix += wsum[w];
        x += prefix;
        cdf[ch * BINS + t] = (float)x / 2000000.0f;   // exact int < 2^24, single rounding
        __syncthreads();
    }
    for (int c = 0; c < 3; c++) {
        float o;
        if (t == 0)             o = 0.0f;
        else if (t == BINS - 1) o = 255.0f;
        else {
            const float v = cdf[c * BINS + t];
            const float* arr = cdf + (3 + c) * BINS;
            int lo = 0, hi = 256;   // lower_bound: first k with arr[k] >= v
            while (lo < hi) { const int mid = (lo + hi) >> 1; if (arr[mid] < v) lo = mid + 1; else hi = mid; }
            const int J0 = ((lo > 1) ? lo : 1) - 1;
            int lo2 = 0, hi2 = 256; // upper_bound: first k with arr[k] > v
            while (lo2 < hi2) { const int mid = (lo2 + hi2) >> 1; if (arr[mid] <= v) lo2 = mid + 1; else hi2 = mid; }
            const int J1 = ((lo2 - 1) < 254 ? (lo2 - 1) : 254);
            const bool found = (lo2 >= 1) && (J0 <= J1);
            o = found ? (float)(J0 + 1) : (float)t;
        }
        tab[c * BINS + t] = o;
    }
    __syncthreads();

    // ---- loss (validated R3 logic; per-block partial) ----
    double local = 0.0;
    const int stride = gridDim.x * 256;
    for (int g = blockIdx.x * 256 + t; g < HH / 4; g += stride) {
        const int p = g * 4;
        const float4 mv = *(const float4*)(msrc + p);
        const unsigned w = bits[p >> 5] >> (p & 31);  // p % 4 == 0: bits never cross a word
        const float m[4] = {mv.x, mv.y, mv.z, mv.w};
#pragma unroll
        for (int c = 0; c < 3; c++) {
            const float4 rv = *(const float4*)(ref + c * HH + p);
            const float4 iv = *(const float4*)(inp + c * HH + p);
            const float r[4] = {rv.x, rv.y, rv.z, rv.w};
            const float x4[4] = {iv.x, iv.y, iv.z, iv.w};
            float s = 0.0f;
#pragma unroll
            for (int k = 0; k < 4; k++) {
                const float mm = m[k];
                const float refm = ((r[k] + 1.0f) * 0.5f) * 255.0f * mm;   // ref_masked
                const float inpm = ((x4[k] + 1.0f) * 0.5f) * 255.0f * mm;  // input_masked
                float matchv;
                if ((w >> k) & 1u) {
                    const int bidx = (int)fminf(fmaxf(refm, 0.0f), 255.0f); // clip-then-trunc
                    matchv = tab[c * BINS + bidx];
                } else {
                    matchv = refm;
                }
                const float dd = inpm - matchv * mm;
                s += dd * dd;
            }
            local += (double)s;
        }
    }
    red[t] = local;
    __syncthreads();
    for (int s2 = 128; s2 > 0; s2 >>= 1) {
        if (t < s2) red[t] += red[t + s2];
        __syncthreads();
    }
    if (t == 0) partials[blockIdx.x] = red[0];

    // ---- last-block finalize ----
    __threadfence();                     // make our partial visible device-wide
    if (t == 0) {
        const unsigned prev = atomicAdd(counter, 1u);
        is_last = (prev == (unsigned)(gridDim.x - 1)) ? 1u : 0u;
    }
    __syncthreads();
    if (is_last) {
        double s = 0.0;
        for (int k = t; k < TL_BLOCKS; k += 256)   // fixed order -> deterministic
            s += __hip_atomic_load(&partials[k], __ATOMIC_RELAXED, __HIP_MEMORY_SCOPE_AGENT);
        red[t] = s;
        __syncthreads();
        for (int s2 = 128; s2 > 0; s2 >>= 1) {
            if (t < s2) red[t] += red[t + s2];
            __syncthreads();
        }
        if (t == 0) out[0] = (float)(red[0] / (double)(3 * HH));
    }
}

extern "C" void kernel_launch(void* const* d_in, const int* in_sizes, int n_in,
                              void* d_out, int out_size, void* d_ws, size_t ws_size,
                              hipStream_t stream)
{
    const float* input_data  = (const float*)d_in[0];
    const float* target_data = (const float*)d_in[1];
    const float* mask_src    = (const float*)d_in[2];
    const float* mask_tar    = (const float*)d_in[3];
    const int*   i0          = (const int*)d_in[4];
    const int*   i1          = (const int*)d_in[5];
    const int*   i2          = (const int*)d_in[6];
    const int*   i3          = (const int*)d_in[7];
    const float* ref_data    = (const float*)d_in[8];
    float* out = (float*)d_out;

    char* ws = (char*)d_ws;
    double*   partials = (double*)(ws + PART_OFF);
    unsigned* counter  = (unsigned*)(ws + CNT_OFF);
    unsigned* hist     = (unsigned*)(ws + HIST_OFF);
    unsigned* bits     = (unsigned*)(ws + BITS_OFF);
    unsigned* packed_d = (unsigned*)(ws + PACKED_D_OFF);
    unsigned* packed_r = (unsigned*)(ws + PACKED_R_OFF);

    pack_kernel<<<2048, 256, 0, stream>>>(ref_data, target_data, mask_src, mask_tar,
                                          packed_d, packed_r, hist, bits, counter);
    hist_kernel<<<2048, 256, 0, stream>>>(packed_d, packed_r, i0, i1, i2, i3, hist, bits);
    tabloss_kernel<<<TL_BLOCKS, 256, 0, stream>>>(input_data, ref_data, mask_src, hist,
                                                  bits, partials, counter, out);
}

// Round 7
// 338.261 us; speedup vs baseline: 1.6366x; 1.6366x over previous
//
#include <hip/hip_runtime.h>

#define HDIM 2048
#define HH (HDIM * HDIM)          // 4,194,304
#define NIDX 2000000
#define BINS 256
#define NCOPY 16
#define TL_BLOCKS 2048            // tabloss grid (partials count)

// workspace layout (bytes)
#define PART_OFF     0                      // double partials[TL_BLOCKS] = 16 KB
#define HIST_OFF     20480                  // uint hist[NCOPY][6][256] = 96 KB
#define BITS_OFF     131072                 // sampled-pixel bitmap, HH/8 = 512 KB
#define PACKED_D_OFF 1048576                // uint packed_d[HH] = 16 MB
#define PACKED_R_OFF 17825792               // uint packed_r[HH] = 16 MB

// Node 1: zero hist/bits + pack 3 channel bins (mask folded: v*0 -> bin 0)
// into bits 0..23 of one uint per pixel.
__global__ __launch_bounds__(256) void pack_kernel(
    const float* __restrict__ ref, const float* __restrict__ tgt,
    const float* __restrict__ msrc, const float* __restrict__ mtar,
    unsigned* __restrict__ packed_d, unsigned* __restrict__ packed_r,
    unsigned* __restrict__ hist, unsigned* __restrict__ bits)
{
    const int gtid = blockIdx.x * 256 + threadIdx.x;
    const int stride = gridDim.x * 256;

    for (int k = gtid; k < NCOPY * 6 * BINS; k += stride) hist[k] = 0;
    for (int k = gtid; k < HH / 32; k += stride) bits[k] = 0;

    for (int g = gtid; g < HH / 4; g += stride) {
        const int p = g * 4;
        const float4 ms4 = *(const float4*)(msrc + p);
        const float4 mt4 = *(const float4*)(mtar + p);
        const float ms[4] = {ms4.x, ms4.y, ms4.z, ms4.w};
        const float mt[4] = {mt4.x, mt4.y, mt4.z, mt4.w};
        unsigned od[4] = {0, 0, 0, 0}, orr[4] = {0, 0, 0, 0};
#pragma unroll
        for (int c = 0; c < 3; c++) {
            const float4 rv = *(const float4*)(ref + c * HH + p);
            const float4 tv = *(const float4*)(tgt + c * HH + p);
            const float r[4] = {rv.x, rv.y, rv.z, rv.w};
            const float tt[4] = {tv.x, tv.y, tv.z, tv.w};
#pragma unroll
            for (int k = 0; k < 4; k++) {
                // reference op order: ((x+1)*0.5)*255, then * mask
                const float vd = ((r[k] + 1.0f) * 0.5f) * 255.0f * ms[k];
                const float vr = ((tt[k] + 1.0f) * 0.5f) * 255.0f * mt[k];
                const unsigned bd = (unsigned)(int)fminf(fmaxf(floorf(vd), 0.0f), 255.0f);
                const unsigned br = (unsigned)(int)fminf(fmaxf(floorf(vr), 0.0f), 255.0f);
                od[k]  |= bd << (8 * c);
                orr[k] |= br << (8 * c);
            }
        }
        *(uint4*)(packed_d + p) = make_uint4(od[0], od[1], od[2], od[3]);
        *(uint4*)(packed_r + p) = make_uint4(orr[0], orr[1], orr[2], orr[3]);
    }
}

// Node 2: gather histogram (int4 index loads, 8 gathers in flight per thread)
// + sampled-pixel bitmap.
__global__ __launch_bounds__(256) void hist_kernel(
    const unsigned* __restrict__ packed_d, const unsigned* __restrict__ packed_r,
    const int* __restrict__ i0, const int* __restrict__ i1,
    const int* __restrict__ i2, const int* __restrict__ i3,
    unsigned* __restrict__ hist, unsigned* __restrict__ bits)
{
    __shared__ unsigned lhist[6 * BINS];
    for (int k = threadIdx.x; k < 6 * BINS; k += 256) lhist[k] = 0;
    __syncthreads();

    const int stride = gridDim.x * 256;
    for (int q = blockIdx.x * 256 + threadIdx.x; q < NIDX / 4; q += stride) {
        const int4 a = ((const int4*)i0)[q];
        const int4 b = ((const int4*)i1)[q];
        const int4 c = ((const int4*)i2)[q];
        const int4 d = ((const int4*)i3)[q];
        const int pd[4] = {a.x * HDIM + b.x, a.y * HDIM + b.y, a.z * HDIM + b.z, a.w * HDIM + b.w};
        const int pr[4] = {c.x * HDIM + d.x, c.y * HDIM + d.y, c.z * HDIM + d.z, c.w * HDIM + d.w};
        unsigned wd[4], wr[4];
#pragma unroll
        for (int k = 0; k < 4; k++) wd[k] = packed_d[pd[k]];
#pragma unroll
        for (int k = 0; k < 4; k++) wr[k] = packed_r[pr[k]];
#pragma unroll
        for (int k = 0; k < 4; k++) atomicOr(&bits[pd[k] >> 5], 1u << (pd[k] & 31));
#pragma unroll
        for (int k = 0; k < 4; k++) {
            atomicAdd(&lhist[           ( wd[k]        & 255u)], 1u);
            atomicAdd(&lhist[1 * BINS + ((wd[k] >> 8 ) & 255u)], 1u);
            atomicAdd(&lhist[2 * BINS + ((wd[k] >> 16) & 255u)], 1u);
            atomicAdd(&lhist[3 * BINS + ( wr[k]        & 255u)], 1u);
            atomicAdd(&lhist[4 * BINS + ((wr[k] >> 8 ) & 255u)], 1u);
            atomicAdd(&lhist[5 * BINS + ((wr[k] >> 16) & 255u)], 1u);
        }
    }
    __syncthreads();
    unsigned* h = hist + (blockIdx.x & (NCOPY - 1)) * (6 * BINS);
    for (int k = threadIdx.x; k < 6 * BINS; k += 256) {
        const unsigned v = lhist[k];
        if (v) atomicAdd(&h[k], v);
    }
}

// Node 3: per-block redundant transfer table (deterministic) + streaming loss.
// Plain per-block partial store — NO fences/atomics (the per-thread
// __threadfence() in R6 was the 250us: device-scope fence = L2 flush per wave
// on non-coherent XCD L2s). Cross-dispatch visibility rides on stream order.
__global__ __launch_bounds__(256) void tabloss_kernel(
    const float* __restrict__ inp, const float* __restrict__ ref,
    const float* __restrict__ msrc, const unsigned* __restrict__ hist,
    const unsigned* __restrict__ bits, double* __restrict__ partials)
{
    __shared__ float    cdf[6 * BINS];   // [0..3*BINS)=cdf_d, [3*BINS..6*BINS)=cdf_r
    __shared__ float    tab[3 * BINS];
    __shared__ double   red[256];
    __shared__ unsigned wsum[4];

    const int t    = threadIdx.x;
    const int lane = t & 63;
    const int wid  = t >> 6;

    // ---- transfer table (validated R3 logic: exact int scan -> divide -> bsearch) ----
    for (int ch = 0; ch < 6; ch++) {
        unsigned x = 0;
#pragma unroll
        for (int cp = 0; cp < NCOPY; cp++) x += hist[cp * (6 * BINS) + ch * BINS + t];
#pragma unroll
        for (int d = 1; d < 64; d <<= 1) {
            const unsigned y = __shfl_up(x, d, 64);
            if (lane >= d) x += y;
        }
        if (lane == 63) wsum[wid] = x;
        __syncthreads();
        unsigned prefix = 0;
        for (int w = 0; w < wid; w++) prefix += wsum[w];
        x += prefix;
        cdf[ch * BINS + t] = (float)x / 2000000.0f;   // exact int < 2^24, single rounding
        __syncthreads();
    }
    for (int c = 0; c < 3; c++) {
        float o;
        if (t == 0)             o = 0.0f;
        else if (t == BINS - 1) o = 255.0f;
        else {
            const float v = cdf[c * BINS + t];
            const float* arr = cdf + (3 + c) * BINS;
            int lo = 0, hi = 256;   // lower_bound: first k with arr[k] >= v
            while (lo < hi) { const int mid = (lo + hi) >> 1; if (arr[mid] < v) lo = mid + 1; else hi = mid; }
            const int J0 = ((lo > 1) ? lo : 1) - 1;
            int lo2 = 0, hi2 = 256; // upper_bound: first k with arr[k] > v
            while (lo2 < hi2) { const int mid = (lo2 + hi2) >> 1; if (arr[mid] <= v) lo2 = mid + 1; else hi2 = mid; }
            const int J1 = ((lo2 - 1) < 254 ? (lo2 - 1) : 254);
            const bool found = (lo2 >= 1) && (J0 <= J1);
            o = found ? (float)(J0 + 1) : (float)t;
        }
        tab[c * BINS + t] = o;
    }
    __syncthreads();

    // ---- loss (validated R3 logic; per-block partial) ----
    double local = 0.0;
    const int stride = gridDim.x * 256;
    for (int g = blockIdx.x * 256 + t; g < HH / 4; g += stride) {
        const int p = g * 4;
        const float4 mv = *(const float4*)(msrc + p);
        const unsigned w = bits[p >> 5] >> (p & 31);  // p % 4 == 0: bits never cross a word
        const float m[4] = {mv.x, mv.y, mv.z, mv.w};
#pragma unroll
        for (int c = 0; c < 3; c++) {
            const float4 rv = *(const float4*)(ref + c * HH + p);
            const float4 iv = *(const float4*)(inp + c * HH + p);
            const float r[4] = {rv.x, rv.y, rv.z, rv.w};
            const float x4[4] = {iv.x, iv.y, iv.z, iv.w};
            float s = 0.0f;
#pragma unroll
            for (int k = 0; k < 4; k++) {
                const float mm = m[k];
                const float refm = ((r[k] + 1.0f) * 0.5f) * 255.0f * mm;   // ref_masked
                const float inpm = ((x4[k] + 1.0f) * 0.5f) * 255.0f * mm;  // input_masked
                float matchv;
                if ((w >> k) & 1u) {
                    const int bidx = (int)fminf(fmaxf(refm, 0.0f), 255.0f); // clip-then-trunc
                    matchv = tab[c * BINS + bidx];
                } else {
                    matchv = refm;
                }
                const float dd = inpm - matchv * mm;
                s += dd * dd;
            }
            local += (double)s;
        }
    }
    red[t] = local;
    __syncthreads();
    for (int s2 = 128; s2 > 0; s2 >>= 1) {
        if (t < s2) red[t] += red[t + s2];
        __syncthreads();
    }
    if (t == 0) partials[blockIdx.x] = red[0];
}

// Node 4: single-block finalize (plain loads; stream order guarantees visibility).
__global__ __launch_bounds__(256) void finalize_kernel(
    const double* __restrict__ partials, float* __restrict__ out)
{
    const int t = threadIdx.x;
    double s = 0.0;
    for (int k = t; k < TL_BLOCKS; k += 256) s += partials[k];
    __shared__ double red[256];
    red[t] = s;
    __syncthreads();
    for (int s2 = 128; s2 > 0; s2 >>= 1) {
        if (t < s2) red[t] += red[t + s2];
        __syncthreads();
    }
    if (t == 0) out[0] = (float)(red[0] / (double)(3 * HH));
}

extern "C" void kernel_launch(void* const* d_in, const int* in_sizes, int n_in,
                              void* d_out, int out_size, void* d_ws, size_t ws_size,
                              hipStream_t stream)
{
    const float* input_data  = (const float*)d_in[0];
    const float* target_data = (const float*)d_in[1];
    const float* mask_src    = (const float*)d_in[2];
    const float* mask_tar    = (const float*)d_in[3];
    const int*   i0          = (const int*)d_in[4];
    const int*   i1          = (const int*)d_in[5];
    const int*   i2          = (const int*)d_in[6];
    const int*   i3          = (const int*)d_in[7];
    const float* ref_data    = (const float*)d_in[8];
    float* out = (float*)d_out;

    char* ws = (char*)d_ws;
    double*   partials = (double*)(ws + PART_OFF);
    unsigned* hist     = (unsigned*)(ws + HIST_OFF);
    unsigned* bits     = (unsigned*)(ws + BITS_OFF);
    unsigned* packed_d = (unsigned*)(ws + PACKED_D_OFF);
    unsigned* packed_r = (unsigned*)(ws + PACKED_R_OFF);

    pack_kernel<<<2048, 256, 0, stream>>>(ref_data, target_data, mask_src, mask_tar,
                                          packed_d, packed_r, hist, bits);
    hist_kernel<<<2048, 256, 0, stream>>>(packed_d, packed_r, i0, i1, i2, i3, hist, bits);
    tabloss_kernel<<<TL_BLOCKS, 256, 0, stream>>>(input_data, ref_data, mask_src, hist,
                                                  bits, partials);
    finalize_kernel<<<1, 256, 0, stream>>>(partials, out);
}